// Round 16
// baseline (171.789 us; speedup 1.0000x reference)
//
#include <hip/hip_runtime.h>

typedef __attribute__((ext_vector_type(8))) __bf16 bf16x8;
typedef __attribute__((ext_vector_type(4))) __bf16 bf16x4;
typedef __attribute__((ext_vector_type(4))) float f32x4;

#define DEV static __device__ __forceinline__

DEV void gload_lds16(const void* g, void* l) {
  __builtin_amdgcn_global_load_lds((const __attribute__((address_space(1))) void*)g,
                                   (__attribute__((address_space(3))) void*)l, 16, 0, 0);
}

DEV void lgkm0_sb() {
  asm volatile("s_waitcnt lgkmcnt(0)" ::: "memory");
  __builtin_amdgcn_sched_barrier(0);
}

// ---------------- convert x -> bf16 ----------------
__global__ void cvt_kernel(const float* __restrict__ src, __bf16* __restrict__ dst, int n) {
  int i = (blockIdx.x * 256 + threadIdx.x) * 8;
  if (i >= n) return;
  float4 a = *(const float4*)(src + i);
  float4 b = *(const float4*)(src + i + 4);
  bf16x8 o;
  o[0] = (__bf16)a.x; o[1] = (__bf16)a.y; o[2] = (__bf16)a.z; o[3] = (__bf16)a.w;
  o[4] = (__bf16)b.x; o[5] = (__bf16)b.y; o[6] = (__bf16)b.z; o[7] = (__bf16)b.w;
  *(bf16x8*)(dst + i) = o;
}

// ------------- transpose + convert ALL weights in one launch -------------
__global__ void tcvt_all(const float* __restrict__ wq, const float* __restrict__ wk,
                         const float* __restrict__ wv, const float* __restrict__ wo,
                         __bf16* __restrict__ WqkvT, __bf16* __restrict__ WoT) {
  __shared__ float tile[32][33];
  int bx = blockIdx.x;
  const float* src;
  __bf16* dst;
  int N, n0, drow;
  if (bx < 64)      { src = wq; dst = WqkvT; N = 2048; n0 = bx * 32;        drow = n0; }
  else if (bx < 80) { src = wk; dst = WqkvT; N = 512;  n0 = (bx - 64) * 32; drow = 2048 + n0; }
  else if (bx < 96) { src = wv; dst = WqkvT; N = 512;  n0 = (bx - 80) * 32; drow = 2560 + n0; }
  else              { src = wo; dst = WoT;   N = 2048; n0 = (bx - 96) * 32; drow = n0; }
  int k0 = blockIdx.y * 32;
  int tx = threadIdx.x & 31, ty = threadIdx.x >> 5;
  #pragma unroll
  for (int i = 0; i < 32; i += 8)
    tile[ty + i][tx] = src[(size_t)(k0 + ty + i) * N + n0 + tx];
  __syncthreads();
  #pragma unroll
  for (int i = 0; i < 32; i += 8)
    dst[(size_t)(drow + ty + i) * 2048 + k0 + tx] = (__bf16)tile[tx][ty + i];
}

// ------------- transpose V out of QKV: VT[(b*4+kvh)*128 + d][s] = V[b*1024+s][kvh*128+d] -------------
__global__ void vt_kernel(const __bf16* __restrict__ QKV, __bf16* __restrict__ VT) {
  __shared__ __bf16 t[32][33];
  int sx = blockIdx.x;  // 0..31 s-tile within batch
  int dx = blockIdx.y;  // 0..3  d-tile
  int bk = blockIdx.z;  // 0..15 (b*4+kvh)
  int b = bk >> 2, kvh = bk & 3;
  int tx = threadIdx.x & 31, ty = threadIdx.x >> 5;
  #pragma unroll
  for (int i = 0; i < 32; i += 8)
    t[ty + i][tx] = QKV[(size_t)(b * 1024 + sx * 32 + ty + i) * 3072 + 2560 + kvh * 128 + dx * 32 + tx];
  __syncthreads();
  #pragma unroll
  for (int i = 0; i < 32; i += 8)
    VT[((size_t)bk * 128 + dx * 32 + ty + i) * 1024 + sx * 32 + tx] = t[tx][ty + i];
}

// ================= 8-phase GEMM 256x192 (QKV) — R14-proven (2-tile unroll, static bufs) =================
__global__ __launch_bounds__(512, 2) void gemm8p_qkv(const __bf16* __restrict__ A,
                                                     const __bf16* __restrict__ Bt,
                                                     __bf16* __restrict__ C,
                                                     int M, int N, int K) {
  constexpr int ABYTES = 256 * 64 * 2;   // 32 KB
  constexpr int BBYTES = 192 * 64 * 2;   // 24 KB
  __shared__ alignas(1024) char smem[2 * (ABYTES + BBYTES)];  // 112 KB

  const int tid = threadIdx.x;
  const int l = tid & 63, w = tid >> 6;
  const int wr = w >> 2, wc = w & 3;
  const int g = l >> 4, ln = l & 15;

  const int nbx = gridDim.x;  // 16
  const int nwg = nbx * gridDim.y;
  int lin = blockIdx.y * nbx + blockIdx.x;
  lin = (lin & 7) * (nwg >> 3) + (lin >> 3);  // bijective: 256 % 8 == 0
  const int brow = (lin / nbx) * 256, bcol = (lin % nbx) * 192;

  const __bf16* Ag = A + (size_t)brow * K;
  const __bf16* Bg = Bt + (size_t)bcol * K;
  const int NT = K / 64;  // 32 (even -> 2x unroll safe)

  f32x4 acc[8][3] = {};

  auto chunk = [&](const __bf16* gb, char* lb, int ktc, int sub) {
    int r16 = l >> 2;
    int colb = ((l & 3) * 16) ^ (((l >> 5) & 1) << 5);
    int row = (sub >> 1) * 16 + r16;
    gload_lds16(gb + (size_t)row * K + ktc * 64 + (sub & 1) * 32 + (colb >> 1),
                lb + sub * 1024 + l * 16);
  };
  auto stA0 = [&](int ktc, char* ab) {
    #pragma unroll
    for (int i = 0; i < 2; ++i) { int idx = i * 8 + w; chunk(Ag, ab, ktc, (idx >> 3) * 16 + (idx & 7)); }
  };
  auto stA1 = [&](int ktc, char* ab) {
    #pragma unroll
    for (int i = 0; i < 2; ++i) { int idx = i * 8 + w; chunk(Ag, ab, ktc, 8 + (idx >> 3) * 16 + (idx & 7)); }
  };
  auto stBg0 = [&](int ktc, char* bb) {
    #pragma unroll
    for (int i = 0; i < 2; ++i) {
      int t = i * 8 + w;
      int sub = ((t >> 2) * 3 + ((t >> 1) & 1)) * 2 + (t & 1);
      chunk(Bg, bb, ktc, sub);
    }
  };
  auto stBg1 = [&](int ktc, char* bb) {
    int sub = ((w >> 1) * 3 + 2) * 2 + (w & 1);
    chunk(Bg, bb, ktc, sub);
  };

  auto ldA = [&](const char* ab, int m, int kk) -> bf16x8 {
    int sub = (wr * 8 + m) * 2 + kk;
    return *(const bf16x8*)(ab + sub * 1024 + ln * 64 + ((g * 16) ^ (((ln >> 3) & 1) << 5)));
  };
  auto ldB = [&](const char* bb, int nf, int kk) -> bf16x8 {
    int sub = (wc * 3 + nf) * 2 + kk;
    return *(const bf16x8*)(bb + sub * 1024 + ln * 64 + ((g * 16) ^ (((ln >> 3) & 1) << 5)));
  };

  auto bar = [&]() {
    __builtin_amdgcn_sched_barrier(0);
    __builtin_amdgcn_s_barrier();
    __builtin_amdgcn_sched_barrier(0);
  };

  char* const A0 = smem;
  char* const A1 = smem + ABYTES;
  char* const B0 = smem + 2 * ABYTES;
  char* const B1 = smem + 2 * ABYTES + BBYTES;

  stA0(0, A0); stBg0(0, B0); stBg1(0, B0); stA1(0, A0);
  stA0(1, A1); stBg0(1, B1); stBg1(1, B1); stA1(1, A1);
  asm volatile("s_waitcnt vmcnt(10)" ::: "memory");
  __builtin_amdgcn_sched_barrier(0);
  bar();

  bf16x8 af[4][2], bfv[3][2];

#define QKV_TILE(KT, AB, BB)                                                                      \
  do {                                                                                            \
    const int ktc = ((KT) + 2) & 31;                                                              \
    _Pragma("unroll")                                                                             \
    for (int m = 0; m < 4; ++m) { af[m][0] = ldA(AB, m, 0); af[m][1] = ldA(AB, m, 1); }           \
    _Pragma("unroll")                                                                             \
    for (int nf = 0; nf < 2; ++nf) { bfv[nf][0] = ldB(BB, nf, 0); bfv[nf][1] = ldB(BB, nf, 1); }  \
    bar();                                                                                        \
    lgkm0_sb();                                                                                   \
    __builtin_amdgcn_s_setprio(1);                                                                \
    _Pragma("unroll")                                                                             \
    for (int m = 0; m < 4; ++m)                                                                   \
      _Pragma("unroll")                                                                           \
      for (int nf = 0; nf < 2; ++nf)                                                              \
        _Pragma("unroll")                                                                         \
        for (int kk = 0; kk < 2; ++kk)                                                            \
          acc[m][nf] = __builtin_amdgcn_mfma_f32_16x16x32_bf16(af[m][kk], bfv[nf][kk],            \
                                                               acc[m][nf], 0, 0, 0);              \
    __builtin_amdgcn_s_setprio(0);                                                                \
    asm volatile("s_waitcnt vmcnt(9)" ::: "memory");                                              \
    __builtin_amdgcn_sched_barrier(0);                                                            \
    bar();                                                                                        \
    bfv[2][0] = ldB(BB, 2, 0); bfv[2][1] = ldB(BB, 2, 1);                                         \
    stA0(ktc, AB); stBg0(ktc, BB);                                                                \
    bar();                                                                                        \
    lgkm0_sb();                                                                                   \
    __builtin_amdgcn_s_setprio(1);                                                                \
    _Pragma("unroll")                                                                             \
    for (int m = 0; m < 4; ++m)                                                                   \
      _Pragma("unroll")                                                                           \
      for (int kk = 0; kk < 2; ++kk)                                                              \
        acc[m][2] = __builtin_amdgcn_mfma_f32_16x16x32_bf16(af[m][kk], bfv[2][kk],                \
                                                            acc[m][2], 0, 0, 0);                  \
    __builtin_amdgcn_s_setprio(0);                                                                \
    asm volatile("s_waitcnt vmcnt(11)" ::: "memory");                                             \
    __builtin_amdgcn_sched_barrier(0);                                                            \
    bar();                                                                                        \
    _Pragma("unroll")                                                                             \
    for (int m = 0; m < 4; ++m) { af[m][0] = ldA(AB, 4 + m, 0); af[m][1] = ldA(AB, 4 + m, 1); }   \
    stBg1(ktc, BB);                                                                               \
    bar();                                                                                        \
    lgkm0_sb();                                                                                   \
    __builtin_amdgcn_s_setprio(1);                                                                \
    _Pragma("unroll")                                                                             \
    for (int m = 0; m < 4; ++m)                                                                   \
      _Pragma("unroll")                                                                           \
      for (int nf = 0; nf < 2; ++nf)                                                              \
        _Pragma("unroll")                                                                         \
        for (int kk = 0; kk < 2; ++kk)                                                            \
          acc[4 + m][nf] = __builtin_amdgcn_mfma_f32_16x16x32_bf16(af[m][kk], bfv[nf][kk],        \
                                                                   acc[4 + m][nf], 0, 0, 0);      \
    __builtin_amdgcn_s_setprio(0);                                                                \
    bar();                                                                                        \
    stA1(ktc, AB);                                                                                \
    bar();                                                                                        \
    lgkm0_sb();                                                                                   \
    __builtin_amdgcn_s_setprio(1);                                                                \
    _Pragma("unroll")                                                                             \
    for (int m = 0; m < 4; ++m)                                                                   \
      _Pragma("unroll")                                                                           \
      for (int kk = 0; kk < 2; ++kk)                                                              \
        acc[4 + m][2] = __builtin_amdgcn_mfma_f32_16x16x32_bf16(af[m][kk], bfv[2][kk],            \
                                                                acc[4 + m][2], 0, 0, 0);          \
    __builtin_amdgcn_s_setprio(0);                                                                \
    asm volatile("s_waitcnt vmcnt(10)" ::: "memory");                                             \
    __builtin_amdgcn_sched_barrier(0);                                                            \
    bar();                                                                                        \
  } while (0)

  for (int ktp = 0; ktp < NT; ktp += 2) {
    QKV_TILE(ktp, A0, B0);
    QKV_TILE(ktp + 1, A1, B1);
  }
#undef QKV_TILE

  #pragma unroll
  for (int mi = 0; mi < 8; ++mi)
    #pragma unroll
    for (int nf = 0; nf < 3; ++nf)
      #pragma unroll
      for (int j = 0; j < 4; ++j) {
        size_t r = brow + wr * 128 + mi * 16 + g * 4 + j;
        size_t c = bcol + wc * 48 + nf * 16 + ln;
        C[r * N + c] = (__bf16)acc[mi][nf][j];
      }
}

// ================= 2-phase GEMM 256x128 (out-proj) — R14-proven =================
__global__ __launch_bounds__(512, 2) void gemm2p(const __bf16* __restrict__ A,
                                                 const __bf16* __restrict__ Bt,
                                                 float* __restrict__ C,
                                                 int M, int N, int K) {
  constexpr int ABYTES = 256 * 64 * 2;   // 32 KB
  constexpr int BBYTES = 128 * 64 * 2;   // 16 KB
  __shared__ alignas(1024) char smem[2 * (ABYTES + BBYTES)];  // 96 KB

  const int tid = threadIdx.x;
  const int l = tid & 63, w = tid >> 6;
  const int wr = w >> 1, wc = w & 1;
  const int g = l >> 4, ln = l & 15;

  const int nbx = gridDim.x;  // 16
  const int nwg = nbx * gridDim.y;
  int lin = blockIdx.y * nbx + blockIdx.x;
  lin = (lin & 7) * (nwg >> 3) + (lin >> 3);
  const int brow = (lin / nbx) * 256, bcol = (lin % nbx) * 128;

  const __bf16* Ag = A + (size_t)brow * K;
  const __bf16* Bg = Bt + (size_t)bcol * K;
  const int NT = K / 64;

  f32x4 acc[4][4] = {};

  auto chunk = [&](const __bf16* gb, char* lb, int ktc, int sub) {
    int r16 = l >> 2;
    int colb = ((l & 3) * 16) ^ (((l >> 5) & 1) << 5);
    int row = (sub >> 1) * 16 + r16;
    gload_lds16(gb + (size_t)row * K + ktc * 64 + (sub & 1) * 32 + (colb >> 1),
                lb + sub * 1024 + l * 16);
  };
  auto stAp0 = [&](int ktc, char* ab) {
    #pragma unroll
    for (int i = 0; i < 2; ++i) { int t = i * 8 + w; chunk(Ag, ab, ktc, (t >> 2) * 8 + (t & 3)); }
  };
  auto stAp1 = [&](int ktc, char* ab) {
    #pragma unroll
    for (int i = 0; i < 2; ++i) { int t = i * 8 + w; chunk(Ag, ab, ktc, (t >> 2) * 8 + 4 + (t & 3)); }
  };
  auto stB = [&](int ktc, char* bb) {
    #pragma unroll
    for (int i = 0; i < 2; ++i) { int t = i * 8 + w; chunk(Bg, bb, ktc, t); }
  };

  auto ldA = [&](const char* ab, int mi, int kk) -> bf16x8 {
    int sub = (wr * 4 + mi) * 2 + kk;
    return *(const bf16x8*)(ab + sub * 1024 + ln * 64 + ((g * 16) ^ (((ln >> 3) & 1) << 5)));
  };
  auto ldB = [&](const char* bb, int nf, int kk) -> bf16x8 {
    int sub = (wc * 4 + nf) * 2 + kk;
    return *(const bf16x8*)(bb + sub * 1024 + ln * 64 + ((g * 16) ^ (((ln >> 3) & 1) << 5)));
  };

  auto vm6 = [&]() {
    asm volatile("s_waitcnt vmcnt(6)" ::: "memory");
    __builtin_amdgcn_sched_barrier(0);
  };
  auto bar = [&]() {
    __builtin_amdgcn_sched_barrier(0);
    __builtin_amdgcn_s_barrier();
    __builtin_amdgcn_sched_barrier(0);
  };

  char* const A0 = smem;
  char* const A1 = smem + ABYTES;
  char* const B0 = smem + 2 * ABYTES;
  char* const B1 = smem + 2 * ABYTES + BBYTES;

  stAp0(0, A0); stB(0, B0);
  stAp1(0, A0);
  stAp0(1, A1); stB(1, B1);
  vm6();
  bar();

  bf16x8 af[2][2], bfv[4][2];

#define OP_TILE(KT, AB, BB, ABo)                                                                  \
  do {                                                                                            \
    const int ktc1 = ((KT) + 1) & 31;                                                             \
    const int ktc2 = ((KT) + 2) & 31;                                                             \
    _Pragma("unroll")                                                                             \
    for (int mi = 0; mi < 2; ++mi) { af[mi][0] = ldA(AB, mi, 0); af[mi][1] = ldA(AB, mi, 1); }    \
    _Pragma("unroll")                                                                             \
    for (int nf = 0; nf < 4; ++nf) { bfv[nf][0] = ldB(BB, nf, 0); bfv[nf][1] = ldB(BB, nf, 1); }  \
    stAp1(ktc1, ABo);                                                                             \
    bar();                                                                                        \
    lgkm0_sb();                                                                                   \
    __builtin_amdgcn_s_setprio(1);                                                                \
    _Pragma("unroll")                                                                             \
    for (int mi = 0; mi < 2; ++mi)                                                                \
      _Pragma("unroll")                                                                           \
      for (int nf = 0; nf < 4; ++nf)                                                              \
        _Pragma("unroll")                                                                         \
        for (int kk = 0; kk < 2; ++kk)                                                            \
          acc[mi][nf] = __builtin_amdgcn_mfma_f32_16x16x32_bf16(af[mi][kk], bfv[nf][kk],          \
                                                                acc[mi][nf], 0, 0, 0);            \
    __builtin_amdgcn_s_setprio(0);                                                                \
    vm6();                                                                                        \
    bar();                                                                                        \
    _Pragma("unroll")                                                                             \
    for (int mi = 0; mi < 2; ++mi) { af[mi][0] = ldA(AB, 2 + mi, 0); af[mi][1] = ldA(AB, 2 + mi, 1); } \
    stAp0(ktc2, AB); stB(ktc2, BB);                                                               \
    bar();                                                                                        \
    lgkm0_sb();                                                                                   \
    __builtin_amdgcn_s_setprio(1);                                                                \
    _Pragma("unroll")                                                                             \
    for (int mi = 0; mi < 2; ++mi)                                                                \
      _Pragma("unroll")                                                                           \
      for (int nf = 0; nf < 4; ++nf)                                                              \
        _Pragma("unroll")                                                                         \
        for (int kk = 0; kk < 2; ++kk)                                                            \
          acc[2 + mi][nf] = __builtin_amdgcn_mfma_f32_16x16x32_bf16(af[mi][kk], bfv[nf][kk],      \
                                                                    acc[2 + mi][nf], 0, 0, 0);    \
    __builtin_amdgcn_s_setprio(0);                                                                \
    vm6();                                                                                        \
    bar();                                                                                        \
  } while (0)

  for (int ktp = 0; ktp < NT; ktp += 2) {
    OP_TILE(ktp, A0, B0, A1);
    OP_TILE(ktp + 1, A1, B1, A0);
  }
#undef OP_TILE

  #pragma unroll
  for (int mi = 0; mi < 4; ++mi)
    #pragma unroll
    for (int nf = 0; nf < 4; ++nf)
      #pragma unroll
      for (int j = 0; j < 4; ++j) {
        size_t r = brow + wr * 64 + mi * 16 + g * 4 + j;
        size_t c = bcol + wc * 64 + nf * 16 + ln;
        C[r * N + c] = acc[mi][nf][j];
      }
}

// ---------------- RoPE in place on K columns of QKV [4096][3072] ----------------
__global__ void ropek_kernel(__bf16* __restrict__ QKV, const float* __restrict__ cosb,
                             const float* __restrict__ sinb) {
  int gid = blockIdx.x * 256 + threadIdx.x;  // total 4096*4*16
  int p = gid & 15;
  int ht = gid >> 4;
  int hc = ht & 3;
  int tok = ht >> 2;
  int s = tok & 1023;
  __bf16* base = QKV + (size_t)tok * 3072 + 2048 + hc * 128;
  int d0 = p * 4;
  const float* cr = cosb + s * 128;
  const float* sr = sinb + s * 128;
  float x0[4], x1[4];
  #pragma unroll
  for (int j = 0; j < 4; ++j) {
    x0[j] = (float)base[d0 + j];
    x1[j] = (float)base[d0 + 64 + j];
  }
  #pragma unroll
  for (int j = 0; j < 4; ++j) {
    float n0 = x0[j] * cr[d0 + j] - x1[j] * sr[d0 + j];
    float n1 = x1[j] * cr[d0 + 64 + j] + x0[j] * sr[d0 + 64 + j];
    base[d0 + j] = (__bf16)n0;
    base[d0 + 64 + j] = (__bf16)n1;
  }
}

// ---------------- Flash attention (causal, GQA) — Q-tile 128, 8 waves ----------------
// Each staged K/V tile now serves 128 q-rows (halves per-wave K/V LDS reads + staging).
// Single barrier per KV-iter (R15-proven); V double-buffered; defer-max (T13).
// Balanced pairs over 8 q-tiles: (x, 7-x) -> uniform 18 iters/block; 256 blocks = 1/CU.
__global__ __launch_bounds__(512, 2) void attn_kernel(const __bf16* __restrict__ QKV,
                                                      const __bf16* __restrict__ VT,
                                                      const float* __restrict__ cosb,
                                                      const float* __restrict__ sinb,
                                                      __bf16* __restrict__ AO) {
  __shared__ __bf16 Kl[2][64 * 128];
  __shared__ __bf16 Vt[2][128 * 64];
  __shared__ __bf16 Pl[8][16 * 72];

  const int tid = threadIdx.x, l = tid & 63, w = tid >> 6;  // w 0..7
  const int h = blockIdx.y, b = blockIdx.z;
  const int kvh = h >> 2;
  const int g = l >> 4, ln = l & 15;
  const __bf16* VTg = VT + (size_t)(b * 4 + kvh) * 128 * 1024;
  const float scsc = 0.08838834764831845f;  // 1/sqrt(128)

  auto stageK = [&](int buf, int kt) {  // 1024 chunks, 2/thread
    const __bf16* Kg = QKV + (size_t)(b * 1024 + kt * 64) * 3072 + 2048 + kvh * 128;
    #pragma unroll
    for (int i = 0; i < 2; ++i) {
      int ci = i * 512 + tid;
      int r = ci >> 4, c = ci & 15;
      int csw = c ^ (r & 7);
      gload_lds16(Kg + (size_t)r * 3072 + csw * 8, (char*)&Kl[buf][0] + (size_t)ci * 16);
    }
  };
  auto stageV = [&](int buf, int kt) {
    #pragma unroll
    for (int i = 0; i < 2; ++i) {
      int ci = i * 512 + tid;
      int row = ci >> 3, c = ci & 7;
      int csw = c ^ (row & 7);
      gload_lds16(VTg + (size_t)row * 1024 + kt * 64 + csw * 8, (char*)&Vt[buf][0] + (size_t)ci * 16);
    }
  };

  #pragma unroll 1
  for (int pass = 0; pass < 2; ++pass) {
    const int qt = pass ? 7 - (int)blockIdx.x : (int)blockIdx.x;
    const size_t tokQ = (size_t)b * 1024 + qt * 128;
    const int srow = qt * 128 + w * 16 + ln;  // global seq position of this lane's q-row

    // Q fragments + in-register RoPE
    bf16x8 qf[4];
    {
      const __bf16* qp = QKV + (tokQ + w * 16 + ln) * 3072 + h * 128;
      bf16x8 qraw[4];
      #pragma unroll
      for (int ks = 0; ks < 4; ++ks) qraw[ks] = *(const bf16x8*)(qp + ks * 32 + g * 8);
      const float* cr = cosb + (size_t)srow * 128;
      const float* sr = sinb + (size_t)srow * 128;
      #pragma unroll
      for (int ks2 = 0; ks2 < 2; ++ks2)
        #pragma unroll
        for (int j = 0; j < 8; ++j) {
          int d = ks2 * 32 + g * 8 + j;
          float lo = (float)qraw[ks2][j], hi = (float)qraw[ks2 + 2][j];
          float c0 = cr[d], s0 = sr[d];
          qf[ks2][j]     = (__bf16)(lo * c0 - hi * s0);
          qf[ks2 + 2][j] = (__bf16)(hi * c0 + lo * s0);
        }
    }

    float mrow = -1e30f, lrow = 0.f;
    f32x4 acco[8] = {};

    __syncthreads();  // previous pass's LDS reads complete before re-staging buf 0
    stageK(0, 0); stageV(0, 0);
    int cur = 0;
    const int last = 2 * qt + 1;

    for (int kt = 0; kt <= last; ++kt) {
      __syncthreads();  // K/V[cur] staged (vmcnt drained); prior reads of [cur^1] done

      if (kt < last) { stageK(cur ^ 1, kt + 1); stageV(cur ^ 1, kt + 1); }

      // ---- S^T = K · Q^T ----
      f32x4 accs[4] = {};
      __builtin_amdgcn_s_setprio(1);
      #pragma unroll
      for (int cb = 0; cb < 4; ++cb) {
        int row = cb * 16 + ln;
        #pragma unroll
        for (int ks = 0; ks < 4; ++ks) {
          bf16x8 kb = *(const bf16x8*)((const char*)&Kl[cur][0] + row * 256 +
                                       (((ks * 4 + g) ^ (row & 7)) * 16));
          accs[cb] = __builtin_amdgcn_mfma_f32_16x16x32_bf16(kb, qf[ks], accs[cb], 0, 0, 0);
        }
      }
      __builtin_amdgcn_s_setprio(0);

      // ---- scale + causal mask (global compare; active only on last 2 tiles) ----
      const bool diag = (kt >= 2 * qt);
      #pragma unroll
      for (int cb = 0; cb < 4; ++cb)
        #pragma unroll
        for (int j = 0; j < 4; ++j) {
          float s = accs[cb][j] * scsc;
          if (diag && (kt * 64 + cb * 16 + g * 4 + j > srow)) s = -1e30f;
          accs[cb][j] = s;
        }

      // ---- online softmax with defer-max (T13, THR=8) ----
      float mt = accs[0][0];
      #pragma unroll
      for (int cb = 0; cb < 4; ++cb)
        #pragma unroll
        for (int j = 0; j < 4; ++j) mt = fmaxf(mt, accs[cb][j]);
      mt = fmaxf(mt, __shfl_xor(mt, 16, 64));
      mt = fmaxf(mt, __shfl_xor(mt, 32, 64));
      if (!__all(mt <= mrow + 8.0f)) {
        float mnew = fmaxf(mrow, mt);
        float corr = __expf(mrow - mnew);
        mrow = mnew;
        lrow *= corr;
        #pragma unroll
        for (int n = 0; n < 8; ++n)
          #pragma unroll
          for (int j = 0; j < 4; ++j) acco[n][j] *= corr;
      }
      float rs = 0.f;
      #pragma unroll
      for (int cb = 0; cb < 4; ++cb)
        #pragma unroll
        for (int j = 0; j < 4; ++j) {
          float p = __expf(accs[cb][j] - mrow);
          accs[cb][j] = p;
          rs += p;
        }
      rs += __shfl_xor(rs, 16, 64);
      rs += __shfl_xor(rs, 32, 64);
      lrow += rs;

      // ---- P -> Pl[w] (wave-private) ----
      #pragma unroll
      for (int cb = 0; cb < 4; ++cb) {
        bf16x4 pw;
        #pragma unroll
        for (int j = 0; j < 4; ++j) pw[j] = (__bf16)accs[cb][j];
        *(bf16x4*)(&Pl[w][ln * 72 + cb * 16 + g * 4]) = pw;
      }
      lgkm0_sb();  // drain own ds_writes; no block barrier needed

      // ---- O^T += V^T · P ----
      __builtin_amdgcn_s_setprio(1);
      #pragma unroll
      for (int sc = 0; sc < 2; ++sc) {
        bf16x8 pa = *(const bf16x8*)(&Pl[w][ln * 72 + sc * 32 + g * 8]);
        #pragma unroll
        for (int n = 0; n < 8; ++n) {
          int row = n * 16 + ln;
          bf16x8 vb = *(const bf16x8*)((const char*)&Vt[cur][0] + row * 128 +
                                       (((sc * 4 + g) ^ (row & 7)) * 16));
          acco[n] = __builtin_amdgcn_mfma_f32_16x16x32_bf16(vb, pa, acco[n], 0, 0, 0);
        }
      }
      __builtin_amdgcn_s_setprio(0);
      cur ^= 1;
    }

    float rl = 1.f / lrow;
    size_t r = tokQ + w * 16 + ln;
    #pragma unroll
    for (int n = 0; n < 8; ++n) {
      bf16x4 ov;
      #pragma unroll
      for (int j = 0; j < 4; ++j) ov[j] = (__bf16)(acco[n][j] * rl);
      *(bf16x4*)(&AO[r * 2048 + h * 128 + n * 16 + g * 4]) = ov;
    }
  }
}

// ---------------- launch ----------------
extern "C" void kernel_launch(void* const* d_in, const int* in_sizes, int n_in,
                              void* d_out, int out_size, void* d_ws, size_t ws_size,
                              hipStream_t stream) {
  const float* x    = (const float*)d_in[0];
  const float* cosb = (const float*)d_in[1];
  const float* sinb = (const float*)d_in[2];
  const float* wq   = (const float*)d_in[3];
  const float* wk   = (const float*)d_in[4];
  const float* wv   = (const float*)d_in[5];
  const float* wo   = (const float*)d_in[6];
  float* out = (float*)d_out;

  char* ws = (char*)d_ws;
  const size_t OFF_XB    = 0;                       // 4096*2048 bf16 = 16 MiB (dead after gemm#1)
  const size_t OFF_WQKVT = OFF_XB + 16777216;       // 3072*2048 bf16 = 12 MiB
  const size_t OFF_WOT   = OFF_WQKVT + 12582912;    // 2048*2048 bf16 = 8 MiB
  const size_t OFF_QKV   = OFF_WOT + 8388608;       // 4096*3072 bf16 = 24 MiB
  const size_t OFF_AO    = OFF_QKV + 25165824;      // 4096*2048 bf16 = 16 MiB
  const size_t OFF_VT    = OFF_XB;                  // 16*128*1024 bf16 = 4 MiB, aliases Xb

  __bf16* Xb    = (__bf16*)(ws + OFF_XB);
  __bf16* WqkvT = (__bf16*)(ws + OFF_WQKVT);
  __bf16* WoT   = (__bf16*)(ws + OFF_WOT);
  __bf16* QKVb  = (__bf16*)(ws + OFF_QKV);
  __bf16* AOb   = (__bf16*)(ws + OFF_AO);
  __bf16* VTb   = (__bf16*)(ws + OFF_VT);

  // 1. convert x
  cvt_kernel<<<4096 * 2048 / 8 / 256, 256, 0, stream>>>(x, Xb, 4096 * 2048);
  // 2. transpose-convert ALL weights (one launch)
  tcvt_all<<<dim3(160, 64), 256, 0, stream>>>(wq, wk, wv, wo, WqkvT, WoT);
  // 3. QKV projection: 8-phase 256x192, 16x16 = 256 blocks (full fill), 2-tile unroll
  gemm8p_qkv<<<dim3(16, 16), 512, 0, stream>>>(Xb, WqkvT, QKVb, 4096, 3072, 2048);
  // 4. transpose V into VT (V is not RoPE'd)
  vt_kernel<<<dim3(32, 4, 16), 256, 0, stream>>>(QKVb, VTb);
  // 5. RoPE K only (Q-rope fused into attention)
  ropek_kernel<<<4096 * 4 * 16 / 256, 256, 0, stream>>>(QKVb, cosb, sinb);
  // 6. attention: Q-tile 128, 8 waves, balanced pairs (x, 7-x)
  attn_kernel<<<dim3(4, 16, 4), 512, 0, stream>>>(QKVb, VTb, cosb, sinb, AOb);
  // 7. output projection: 2-phase 256x128, 16x16 = 256 blocks, 2-tile unroll
  gemm2p<<<dim3(16, 16), 512, 0, stream>>>(AOb, WoT, out, 4096, 2048, 2048);
}

// Round 17
// 164.836 us; speedup vs baseline: 1.0422x; 1.0422x over previous
//
#include <hip/hip_runtime.h>

typedef __attribute__((ext_vector_type(8))) __bf16 bf16x8;
typedef __attribute__((ext_vector_type(4))) __bf16 bf16x4;
typedef __attribute__((ext_vector_type(4))) float f32x4;

#define DEV static __device__ __forceinline__

DEV void gload_lds16(const void* g, void* l) {
  __builtin_amdgcn_global_load_lds((const __attribute__((address_space(1))) void*)g,
                                   (__attribute__((address_space(3))) void*)l, 16, 0, 0);
}

DEV void lgkm0_sb() {
  asm volatile("s_waitcnt lgkmcnt(0)" ::: "memory");
  __builtin_amdgcn_sched_barrier(0);
}

// ------------- prep: transpose-convert all weights + convert x, ONE launch -------------
// bx [0,64)  wq -> WqkvT rows 0..2047      bx [64,80)  wk -> rows 2048..2559
// bx [80,96) wv -> rows 2560..3071         bx [96,160) wo -> WoT rows 0..2047
// bx [160,224): cvt x (f32 -> bf16), virtual block (bx-160)*64 + by over 8M elems
__global__ void prep_all(const float* __restrict__ x, const float* __restrict__ wq,
                         const float* __restrict__ wk, const float* __restrict__ wv,
                         const float* __restrict__ wo, __bf16* __restrict__ Xb,
                         __bf16* __restrict__ WqkvT, __bf16* __restrict__ WoT) {
  int bx = blockIdx.x;
  if (bx >= 160) {
    size_t vb = (size_t)(bx - 160) * 64 + blockIdx.y;
    size_t i = (vb * 256 + threadIdx.x) * 8;
    float4 a = *(const float4*)(x + i);
    float4 b = *(const float4*)(x + i + 4);
    bf16x8 o;
    o[0] = (__bf16)a.x; o[1] = (__bf16)a.y; o[2] = (__bf16)a.z; o[3] = (__bf16)a.w;
    o[4] = (__bf16)b.x; o[5] = (__bf16)b.y; o[6] = (__bf16)b.z; o[7] = (__bf16)b.w;
    *(bf16x8*)(Xb + i) = o;
    return;
  }
  __shared__ float tile[32][33];
  const float* src;
  __bf16* dst;
  int N, n0, drow;
  if (bx < 64)      { src = wq; dst = WqkvT; N = 2048; n0 = bx * 32;        drow = n0; }
  else if (bx < 80) { src = wk; dst = WqkvT; N = 512;  n0 = (bx - 64) * 32; drow = 2048 + n0; }
  else if (bx < 96) { src = wv; dst = WqkvT; N = 512;  n0 = (bx - 80) * 32; drow = 2560 + n0; }
  else              { src = wo; dst = WoT;   N = 2048; n0 = (bx - 96) * 32; drow = n0; }
  int k0 = blockIdx.y * 32;
  int tx = threadIdx.x & 31, ty = threadIdx.x >> 5;
  #pragma unroll
  for (int i = 0; i < 32; i += 8)
    tile[ty + i][tx] = src[(size_t)(k0 + ty + i) * N + n0 + tx];
  __syncthreads();
  #pragma unroll
  for (int i = 0; i < 32; i += 8)
    dst[(size_t)(drow + ty + i) * 2048 + k0 + tx] = (__bf16)tile[tx][ty + i];
}

// ------------- transpose V out of QKV: VT[(b*4+kvh)*128 + d][s] = V[b*1024+s][kvh*128+d] -------------
__global__ void vt_kernel(const __bf16* __restrict__ QKV, __bf16* __restrict__ VT) {
  __shared__ __bf16 t[32][33];
  int sx = blockIdx.x;
  int dx = blockIdx.y;
  int bk = blockIdx.z;
  int b = bk >> 2, kvh = bk & 3;
  int tx = threadIdx.x & 31, ty = threadIdx.x >> 5;
  #pragma unroll
  for (int i = 0; i < 32; i += 8)
    t[ty + i][tx] = QKV[(size_t)(b * 1024 + sx * 32 + ty + i) * 3072 + 2560 + kvh * 128 + dx * 32 + tx];
  __syncthreads();
  #pragma unroll
  for (int i = 0; i < 32; i += 8)
    VT[((size_t)bk * 128 + dx * 32 + ty + i) * 1024 + sx * 32 + tx] = t[tx][ty + i];
}

// ================= 8-phase GEMM 256x192 (QKV) — R14-proven (2-tile unroll, static bufs) =================
__global__ __launch_bounds__(512, 2) void gemm8p_qkv(const __bf16* __restrict__ A,
                                                     const __bf16* __restrict__ Bt,
                                                     __bf16* __restrict__ C,
                                                     int M, int N, int K) {
  constexpr int ABYTES = 256 * 64 * 2;   // 32 KB
  constexpr int BBYTES = 192 * 64 * 2;   // 24 KB
  __shared__ alignas(1024) char smem[2 * (ABYTES + BBYTES)];  // 112 KB

  const int tid = threadIdx.x;
  const int l = tid & 63, w = tid >> 6;
  const int wr = w >> 2, wc = w & 3;
  const int g = l >> 4, ln = l & 15;

  const int nbx = gridDim.x;  // 16
  const int nwg = nbx * gridDim.y;
  int lin = blockIdx.y * nbx + blockIdx.x;
  lin = (lin & 7) * (nwg >> 3) + (lin >> 3);  // bijective: 256 % 8 == 0
  const int brow = (lin / nbx) * 256, bcol = (lin % nbx) * 192;

  const __bf16* Ag = A + (size_t)brow * K;
  const __bf16* Bg = Bt + (size_t)bcol * K;
  const int NT = K / 64;  // 32

  f32x4 acc[8][3] = {};

  auto chunk = [&](const __bf16* gb, char* lb, int ktc, int sub) {
    int r16 = l >> 2;
    int colb = ((l & 3) * 16) ^ (((l >> 5) & 1) << 5);
    int row = (sub >> 1) * 16 + r16;
    gload_lds16(gb + (size_t)row * K + ktc * 64 + (sub & 1) * 32 + (colb >> 1),
                lb + sub * 1024 + l * 16);
  };
  auto stA0 = [&](int ktc, char* ab) {
    #pragma unroll
    for (int i = 0; i < 2; ++i) { int idx = i * 8 + w; chunk(Ag, ab, ktc, (idx >> 3) * 16 + (idx & 7)); }
  };
  auto stA1 = [&](int ktc, char* ab) {
    #pragma unroll
    for (int i = 0; i < 2; ++i) { int idx = i * 8 + w; chunk(Ag, ab, ktc, 8 + (idx >> 3) * 16 + (idx & 7)); }
  };
  auto stBg0 = [&](int ktc, char* bb) {
    #pragma unroll
    for (int i = 0; i < 2; ++i) {
      int t = i * 8 + w;
      int sub = ((t >> 2) * 3 + ((t >> 1) & 1)) * 2 + (t & 1);
      chunk(Bg, bb, ktc, sub);
    }
  };
  auto stBg1 = [&](int ktc, char* bb) {
    int sub = ((w >> 1) * 3 + 2) * 2 + (w & 1);
    chunk(Bg, bb, ktc, sub);
  };

  auto ldA = [&](const char* ab, int m, int kk) -> bf16x8 {
    int sub = (wr * 8 + m) * 2 + kk;
    return *(const bf16x8*)(ab + sub * 1024 + ln * 64 + ((g * 16) ^ (((ln >> 3) & 1) << 5)));
  };
  auto ldB = [&](const char* bb, int nf, int kk) -> bf16x8 {
    int sub = (wc * 3 + nf) * 2 + kk;
    return *(const bf16x8*)(bb + sub * 1024 + ln * 64 + ((g * 16) ^ (((ln >> 3) & 1) << 5)));
  };

  auto bar = [&]() {
    __builtin_amdgcn_sched_barrier(0);
    __builtin_amdgcn_s_barrier();
    __builtin_amdgcn_sched_barrier(0);
  };

  char* const A0 = smem;
  char* const A1 = smem + ABYTES;
  char* const B0 = smem + 2 * ABYTES;
  char* const B1 = smem + 2 * ABYTES + BBYTES;

  stA0(0, A0); stBg0(0, B0); stBg1(0, B0); stA1(0, A0);
  stA0(1, A1); stBg0(1, B1); stBg1(1, B1); stA1(1, A1);
  asm volatile("s_waitcnt vmcnt(10)" ::: "memory");
  __builtin_amdgcn_sched_barrier(0);
  bar();

  bf16x8 af[4][2], bfv[3][2];

#define QKV_TILE(KT, AB, BB)                                                                      \
  do {                                                                                            \
    const int ktc = ((KT) + 2) & 31;                                                              \
    _Pragma("unroll")                                                                             \
    for (int m = 0; m < 4; ++m) { af[m][0] = ldA(AB, m, 0); af[m][1] = ldA(AB, m, 1); }           \
    _Pragma("unroll")                                                                             \
    for (int nf = 0; nf < 2; ++nf) { bfv[nf][0] = ldB(BB, nf, 0); bfv[nf][1] = ldB(BB, nf, 1); }  \
    bar();                                                                                        \
    lgkm0_sb();                                                                                   \
    __builtin_amdgcn_s_setprio(1);                                                                \
    _Pragma("unroll")                                                                             \
    for (int m = 0; m < 4; ++m)                                                                   \
      _Pragma("unroll")                                                                           \
      for (int nf = 0; nf < 2; ++nf)                                                              \
        _Pragma("unroll")                                                                         \
        for (int kk = 0; kk < 2; ++kk)                                                            \
          acc[m][nf] = __builtin_amdgcn_mfma_f32_16x16x32_bf16(af[m][kk], bfv[nf][kk],            \
                                                               acc[m][nf], 0, 0, 0);              \
    __builtin_amdgcn_s_setprio(0);                                                                \
    asm volatile("s_waitcnt vmcnt(9)" ::: "memory");                                              \
    __builtin_amdgcn_sched_barrier(0);                                                            \
    bar();                                                                                        \
    bfv[2][0] = ldB(BB, 2, 0); bfv[2][1] = ldB(BB, 2, 1);                                         \
    stA0(ktc, AB); stBg0(ktc, BB);                                                                \
    bar();                                                                                        \
    lgkm0_sb();                                                                                   \
    __builtin_amdgcn_s_setprio(1);                                                                \
    _Pragma("unroll")                                                                             \
    for (int m = 0; m < 4; ++m)                                                                   \
      _Pragma("unroll")                                                                           \
      for (int kk = 0; kk < 2; ++kk)                                                              \
        acc[m][2] = __builtin_amdgcn_mfma_f32_16x16x32_bf16(af[m][kk], bfv[2][kk],                \
                                                            acc[m][2], 0, 0, 0);                  \
    __builtin_amdgcn_s_setprio(0);                                                                \
    asm volatile("s_waitcnt vmcnt(11)" ::: "memory");                                             \
    __builtin_amdgcn_sched_barrier(0);                                                            \
    bar();                                                                                        \
    _Pragma("unroll")                                                                             \
    for (int m = 0; m < 4; ++m) { af[m][0] = ldA(AB, 4 + m, 0); af[m][1] = ldA(AB, 4 + m, 1); }   \
    stBg1(ktc, BB);                                                                               \
    bar();                                                                                        \
    lgkm0_sb();                                                                                   \
    __builtin_amdgcn_s_setprio(1);                                                                \
    _Pragma("unroll")                                                                             \
    for (int m = 0; m < 4; ++m)                                                                   \
      _Pragma("unroll")                                                                           \
      for (int nf = 0; nf < 2; ++nf)                                                              \
        _Pragma("unroll")                                                                         \
        for (int kk = 0; kk < 2; ++kk)                                                            \
          acc[4 + m][nf] = __builtin_amdgcn_mfma_f32_16x16x32_bf16(af[m][kk], bfv[nf][kk],        \
                                                                   acc[4 + m][nf], 0, 0, 0);      \
    __builtin_amdgcn_s_setprio(0);                                                                \
    bar();                                                                                        \
    stA1(ktc, AB);                                                                                \
    bar();                                                                                        \
    lgkm0_sb();                                                                                   \
    __builtin_amdgcn_s_setprio(1);                                                                \
    _Pragma("unroll")                                                                             \
    for (int m = 0; m < 4; ++m)                                                                   \
      _Pragma("unroll")                                                                           \
      for (int kk = 0; kk < 2; ++kk)                                                              \
        acc[4 + m][2] = __builtin_amdgcn_mfma_f32_16x16x32_bf16(af[m][kk], bfv[2][kk],            \
                                                                acc[4 + m][2], 0, 0, 0);          \
    __builtin_amdgcn_s_setprio(0);                                                                \
    asm volatile("s_waitcnt vmcnt(10)" ::: "memory");                                             \
    __builtin_amdgcn_sched_barrier(0);                                                            \
    bar();                                                                                        \
  } while (0)

  for (int ktp = 0; ktp < NT; ktp += 2) {
    QKV_TILE(ktp, A0, B0);
    QKV_TILE(ktp + 1, A1, B1);
  }
#undef QKV_TILE

  #pragma unroll
  for (int mi = 0; mi < 8; ++mi)
    #pragma unroll
    for (int nf = 0; nf < 3; ++nf)
      #pragma unroll
      for (int j = 0; j < 4; ++j) {
        size_t r = brow + wr * 128 + mi * 16 + g * 4 + j;
        size_t c = bcol + wc * 48 + nf * 16 + ln;
        C[r * N + c] = (__bf16)acc[mi][nf][j];
      }
}

// ================= 2-phase GEMM 256x128 (out-proj) — R14-proven =================
__global__ __launch_bounds__(512, 2) void gemm2p(const __bf16* __restrict__ A,
                                                 const __bf16* __restrict__ Bt,
                                                 float* __restrict__ C,
                                                 int M, int N, int K) {
  constexpr int ABYTES = 256 * 64 * 2;   // 32 KB
  constexpr int BBYTES = 128 * 64 * 2;   // 16 KB
  __shared__ alignas(1024) char smem[2 * (ABYTES + BBYTES)];  // 96 KB

  const int tid = threadIdx.x;
  const int l = tid & 63, w = tid >> 6;
  const int wr = w >> 1, wc = w & 1;
  const int g = l >> 4, ln = l & 15;

  const int nbx = gridDim.x;  // 16
  const int nwg = nbx * gridDim.y;
  int lin = blockIdx.y * nbx + blockIdx.x;
  lin = (lin & 7) * (nwg >> 3) + (lin >> 3);
  const int brow = (lin / nbx) * 256, bcol = (lin % nbx) * 128;

  const __bf16* Ag = A + (size_t)brow * K;
  const __bf16* Bg = Bt + (size_t)bcol * K;
  const int NT = K / 64;

  f32x4 acc[4][4] = {};

  auto chunk = [&](const __bf16* gb, char* lb, int ktc, int sub) {
    int r16 = l >> 2;
    int colb = ((l & 3) * 16) ^ (((l >> 5) & 1) << 5);
    int row = (sub >> 1) * 16 + r16;
    gload_lds16(gb + (size_t)row * K + ktc * 64 + (sub & 1) * 32 + (colb >> 1),
                lb + sub * 1024 + l * 16);
  };
  auto stAp0 = [&](int ktc, char* ab) {
    #pragma unroll
    for (int i = 0; i < 2; ++i) { int t = i * 8 + w; chunk(Ag, ab, ktc, (t >> 2) * 8 + (t & 3)); }
  };
  auto stAp1 = [&](int ktc, char* ab) {
    #pragma unroll
    for (int i = 0; i < 2; ++i) { int t = i * 8 + w; chunk(Ag, ab, ktc, (t >> 2) * 8 + 4 + (t & 3)); }
  };
  auto stB = [&](int ktc, char* bb) {
    #pragma unroll
    for (int i = 0; i < 2; ++i) { int t = i * 8 + w; chunk(Bg, bb, ktc, t); }
  };

  auto ldA = [&](const char* ab, int mi, int kk) -> bf16x8 {
    int sub = (wr * 4 + mi) * 2 + kk;
    return *(const bf16x8*)(ab + sub * 1024 + ln * 64 + ((g * 16) ^ (((ln >> 3) & 1) << 5)));
  };
  auto ldB = [&](const char* bb, int nf, int kk) -> bf16x8 {
    int sub = (wc * 4 + nf) * 2 + kk;
    return *(const bf16x8*)(bb + sub * 1024 + ln * 64 + ((g * 16) ^ (((ln >> 3) & 1) << 5)));
  };

  auto vm6 = [&]() {
    asm volatile("s_waitcnt vmcnt(6)" ::: "memory");
    __builtin_amdgcn_sched_barrier(0);
  };
  auto bar = [&]() {
    __builtin_amdgcn_sched_barrier(0);
    __builtin_amdgcn_s_barrier();
    __builtin_amdgcn_sched_barrier(0);
  };

  char* const A0 = smem;
  char* const A1 = smem + ABYTES;
  char* const B0 = smem + 2 * ABYTES;
  char* const B1 = smem + 2 * ABYTES + BBYTES;

  stAp0(0, A0); stB(0, B0);
  stAp1(0, A0);
  stAp0(1, A1); stB(1, B1);
  vm6();
  bar();

  bf16x8 af[2][2], bfv[4][2];

#define OP_TILE(KT, AB, BB, ABo)                                                                  \
  do {                                                                                            \
    const int ktc1 = ((KT) + 1) & 31;                                                             \
    const int ktc2 = ((KT) + 2) & 31;                                                             \
    _Pragma("unroll")                                                                             \
    for (int mi = 0; mi < 2; ++mi) { af[mi][0] = ldA(AB, mi, 0); af[mi][1] = ldA(AB, mi, 1); }    \
    _Pragma("unroll")                                                                             \
    for (int nf = 0; nf < 4; ++nf) { bfv[nf][0] = ldB(BB, nf, 0); bfv[nf][1] = ldB(BB, nf, 1); }  \
    stAp1(ktc1, ABo);                                                                             \
    bar();                                                                                        \
    lgkm0_sb();                                                                                   \
    __builtin_amdgcn_s_setprio(1);                                                                \
    _Pragma("unroll")                                                                             \
    for (int mi = 0; mi < 2; ++mi)                                                                \
      _Pragma("unroll")                                                                           \
      for (int nf = 0; nf < 4; ++nf)                                                              \
        _Pragma("unroll")                                                                         \
        for (int kk = 0; kk < 2; ++kk)                                                            \
          acc[mi][nf] = __builtin_amdgcn_mfma_f32_16x16x32_bf16(af[mi][kk], bfv[nf][kk],          \
                                                                acc[mi][nf], 0, 0, 0);            \
    __builtin_amdgcn_s_setprio(0);                                                                \
    vm6();                                                                                        \
    bar();                                                                                        \
    _Pragma("unroll")                                                                             \
    for (int mi = 0; mi < 2; ++mi) { af[mi][0] = ldA(AB, 2 + mi, 0); af[mi][1] = ldA(AB, 2 + mi, 1); } \
    stAp0(ktc2, AB); stB(ktc2, BB);                                                               \
    bar();                                                                                        \
    lgkm0_sb();                                                                                   \
    __builtin_amdgcn_s_setprio(1);                                                                \
    _Pragma("unroll")                                                                             \
    for (int mi = 0; mi < 2; ++mi)                                                                \
      _Pragma("unroll")                                                                           \
      for (int nf = 0; nf < 4; ++nf)                                                              \
        _Pragma("unroll")                                                                         \
        for (int kk = 0; kk < 2; ++kk)                                                            \
          acc[2 + mi][nf] = __builtin_amdgcn_mfma_f32_16x16x32_bf16(af[mi][kk], bfv[nf][kk],      \
                                                                    acc[2 + mi][nf], 0, 0, 0);    \
    __builtin_amdgcn_s_setprio(0);                                                                \
    vm6();                                                                                        \
    bar();                                                                                        \
  } while (0)

  for (int ktp = 0; ktp < NT; ktp += 2) {
    OP_TILE(ktp, A0, B0, A1);
    OP_TILE(ktp + 1, A1, B1, A0);
  }
#undef OP_TILE

  #pragma unroll
  for (int mi = 0; mi < 4; ++mi)
    #pragma unroll
    for (int nf = 0; nf < 4; ++nf)
      #pragma unroll
      for (int j = 0; j < 4; ++j) {
        size_t r = brow + wr * 64 + mi * 16 + g * 4 + j;
        size_t c = bcol + wc * 64 + nf * 16 + ln;
        C[r * N + c] = acc[mi][nf][j];
      }
}

// ---------------- RoPE in place on K columns of QKV [4096][3072] ----------------
__global__ void ropek_kernel(__bf16* __restrict__ QKV, const float* __restrict__ cosb,
                             const float* __restrict__ sinb) {
  int gid = blockIdx.x * 256 + threadIdx.x;  // total 4096*4*16
  int p = gid & 15;
  int ht = gid >> 4;
  int hc = ht & 3;
  int tok = ht >> 2;
  int s = tok & 1023;
  __bf16* base = QKV + (size_t)tok * 3072 + 2048 + hc * 128;
  int d0 = p * 4;
  const float* cr = cosb + s * 128;
  const float* sr = sinb + s * 128;
  float x0[4], x1[4];
  #pragma unroll
  for (int j = 0; j < 4; ++j) {
    x0[j] = (float)base[d0 + j];
    x1[j] = (float)base[d0 + 64 + j];
  }
  #pragma unroll
  for (int j = 0; j < 4; ++j) {
    float n0 = x0[j] * cr[d0 + j] - x1[j] * sr[d0 + j];
    float n1 = x1[j] * cr[d0 + 64 + j] + x0[j] * sr[d0 + 64 + j];
    base[d0 + j] = (__bf16)n0;
    base[d0 + 64 + j] = (__bf16)n1;
  }
}

// ---------------- Flash attention (R15-proven): Q-tile 64, 4 waves, 2 blocks/CU ----------------
// Single barrier per KV-iter; V double-buffered; Pl wave-private (lgkmcnt-only); defer-max.
__global__ __launch_bounds__(256, 2) void attn_kernel(const __bf16* __restrict__ QKV,
                                                      const __bf16* __restrict__ VT,
                                                      const float* __restrict__ cosb,
                                                      const float* __restrict__ sinb,
                                                      __bf16* __restrict__ AO) {
  __shared__ __bf16 Kl[2][64 * 128];
  __shared__ __bf16 Vt[2][128 * 64];
  __shared__ __bf16 Pl[4][16 * 72];

  const int tid = threadIdx.x, l = tid & 63, w = tid >> 6;
  const int h = blockIdx.y, b = blockIdx.z;
  const int kvh = h >> 2;
  const int g = l >> 4, ln = l & 15;
  const __bf16* VTg = VT + (size_t)(b * 4 + kvh) * 128 * 1024;
  const float scsc = 0.08838834764831845f;  // 1/sqrt(128)

  auto stageK = [&](int buf, int kt) {
    const __bf16* Kg = QKV + (size_t)(b * 1024 + kt * 64) * 3072 + 2048 + kvh * 128;
    #pragma unroll
    for (int i = 0; i < 4; ++i) {
      int r = i * 16 + (tid >> 4);
      int c = tid & 15;
      int csw = c ^ (r & 7);
      gload_lds16(Kg + (size_t)r * 3072 + csw * 8, (char*)&Kl[buf][0] + i * 4096 + tid * 16);
    }
  };
  auto stageV = [&](int buf, int kt) {
    #pragma unroll
    for (int i = 0; i < 4; ++i) {
      int ci = i * 256 + tid;
      int row = ci >> 3;
      int c = ci & 7;
      int csw = c ^ (row & 7);
      gload_lds16(VTg + (size_t)row * 1024 + kt * 64 + csw * 8, (char*)&Vt[buf][0] + (size_t)ci * 16);
    }
  };

  #pragma unroll 1
  for (int pass = 0; pass < 2; ++pass) {
    const int qt = pass ? 15 - (int)blockIdx.x : (int)blockIdx.x;
    const size_t tokQ = (size_t)b * 1024 + qt * 64;
    const int srow = qt * 64 + w * 16 + ln;

    // Q fragments + in-register RoPE
    bf16x8 qf[4];
    {
      const __bf16* qp = QKV + (tokQ + w * 16 + ln) * 3072 + h * 128;
      bf16x8 qraw[4];
      #pragma unroll
      for (int ks = 0; ks < 4; ++ks) qraw[ks] = *(const bf16x8*)(qp + ks * 32 + g * 8);
      const float* cr = cosb + (size_t)srow * 128;
      const float* sr = sinb + (size_t)srow * 128;
      #pragma unroll
      for (int ks2 = 0; ks2 < 2; ++ks2)
        #pragma unroll
        for (int j = 0; j < 8; ++j) {
          int d = ks2 * 32 + g * 8 + j;
          float lo = (float)qraw[ks2][j], hi = (float)qraw[ks2 + 2][j];
          float c0 = cr[d], s0 = sr[d];
          qf[ks2][j]     = (__bf16)(lo * c0 - hi * s0);
          qf[ks2 + 2][j] = (__bf16)(hi * c0 + lo * s0);
        }
    }

    float mrow = -1e30f, lrow = 0.f;
    f32x4 acco[8] = {};

    __syncthreads();  // previous pass's LDS reads complete before re-staging buf 0
    stageK(0, 0); stageV(0, 0);
    int cur = 0;

    for (int kt = 0; kt <= qt; ++kt) {
      __syncthreads();  // K/V[cur] staged (vmcnt drained); prior reads of [cur^1] done

      if (kt < qt) { stageK(cur ^ 1, kt + 1); stageV(cur ^ 1, kt + 1); }

      // ---- S^T = K · Q^T ----
      f32x4 accs[4] = {};
      __builtin_amdgcn_s_setprio(1);
      #pragma unroll
      for (int cb = 0; cb < 4; ++cb) {
        int row = cb * 16 + ln;
        #pragma unroll
        for (int ks = 0; ks < 4; ++ks) {
          bf16x8 kb = *(const bf16x8*)((const char*)&Kl[cur][0] + row * 256 +
                                       (((ks * 4 + g) ^ (row & 7)) * 16));
          accs[cb] = __builtin_amdgcn_mfma_f32_16x16x32_bf16(kb, qf[ks], accs[cb], 0, 0, 0);
        }
      }
      __builtin_amdgcn_s_setprio(0);

      // ---- scale + causal mask ----
      const bool diag = (kt == qt);
      #pragma unroll
      for (int cb = 0; cb < 4; ++cb)
        #pragma unroll
        for (int j = 0; j < 4; ++j) {
          float s = accs[cb][j] * scsc;
          if (diag && (cb * 16 + g * 4 + j > w * 16 + ln)) s = -1e30f;
          accs[cb][j] = s;
        }

      // ---- online softmax with defer-max (T13, THR=8) ----
      float mt = accs[0][0];
      #pragma unroll
      for (int cb = 0; cb < 4; ++cb)
        #pragma unroll
        for (int j = 0; j < 4; ++j) mt = fmaxf(mt, accs[cb][j]);
      mt = fmaxf(mt, __shfl_xor(mt, 16, 64));
      mt = fmaxf(mt, __shfl_xor(mt, 32, 64));
      if (!__all(mt <= mrow + 8.0f)) {
        float mnew = fmaxf(mrow, mt);
        float corr = __expf(mrow - mnew);
        mrow = mnew;
        lrow *= corr;
        #pragma unroll
        for (int n = 0; n < 8; ++n)
          #pragma unroll
          for (int j = 0; j < 4; ++j) acco[n][j] *= corr;
      }
      float rs = 0.f;
      #pragma unroll
      for (int cb = 0; cb < 4; ++cb)
        #pragma unroll
        for (int j = 0; j < 4; ++j) {
          float p = __expf(accs[cb][j] - mrow);
          accs[cb][j] = p;
          rs += p;
        }
      rs += __shfl_xor(rs, 16, 64);
      rs += __shfl_xor(rs, 32, 64);
      lrow += rs;

      // ---- P -> Pl[w] (wave-private) ----
      #pragma unroll
      for (int cb = 0; cb < 4; ++cb) {
        bf16x4 pw;
        #pragma unroll
        for (int j = 0; j < 4; ++j) pw[j] = (__bf16)accs[cb][j];
        *(bf16x4*)(&Pl[w][ln * 72 + cb * 16 + g * 4]) = pw;
      }
      lgkm0_sb();  // drain own ds_writes; no block barrier needed

      // ---- O^T += V^T · P ----
      __builtin_amdgcn_s_setprio(1);
      #pragma unroll
      for (int sc = 0; sc < 2; ++sc) {
        bf16x8 pa = *(const bf16x8*)(&Pl[w][ln * 72 + sc * 32 + g * 8]);
        #pragma unroll
        for (int n = 0; n < 8; ++n) {
          int row = n * 16 + ln;
          bf16x8 vb = *(const bf16x8*)((const char*)&Vt[cur][0] + row * 128 +
                                       (((sc * 4 + g) ^ (row & 7)) * 16));
          acco[n] = __builtin_amdgcn_mfma_f32_16x16x32_bf16(vb, pa, acco[n], 0, 0, 0);
        }
      }
      __builtin_amdgcn_s_setprio(0);
      cur ^= 1;
    }

    float rl = 1.f / lrow;
    size_t r = tokQ + w * 16 + ln;
    #pragma unroll
    for (int n = 0; n < 8; ++n) {
      bf16x4 ov;
      #pragma unroll
      for (int j = 0; j < 4; ++j) ov[j] = (__bf16)(acco[n][j] * rl);
      *(bf16x4*)(&AO[r * 2048 + h * 128 + n * 16 + g * 4]) = ov;
    }
  }
}

// ---------------- launch ----------------
extern "C" void kernel_launch(void* const* d_in, const int* in_sizes, int n_in,
                              void* d_out, int out_size, void* d_ws, size_t ws_size,
                              hipStream_t stream) {
  const float* x    = (const float*)d_in[0];
  const float* cosb = (const float*)d_in[1];
  const float* sinb = (const float*)d_in[2];
  const float* wq   = (const float*)d_in[3];
  const float* wk   = (const float*)d_in[4];
  const float* wv   = (const float*)d_in[5];
  const float* wo   = (const float*)d_in[6];
  float* out = (float*)d_out;

  char* ws = (char*)d_ws;
  const size_t OFF_XB    = 0;                       // 4096*2048 bf16 = 16 MiB (dead after gemm#1)
  const size_t OFF_WQKVT = OFF_XB + 16777216;       // 3072*2048 bf16 = 12 MiB
  const size_t OFF_WOT   = OFF_WQKVT + 12582912;    // 2048*2048 bf16 = 8 MiB
  const size_t OFF_QKV   = OFF_WOT + 8388608;       // 4096*3072 bf16 = 24 MiB
  const size_t OFF_AO    = OFF_QKV + 25165824;      // 4096*2048 bf16 = 16 MiB
  const size_t OFF_VT    = OFF_XB;                  // 16*128*1024 bf16 = 4 MiB, aliases Xb

  __bf16* Xb    = (__bf16*)(ws + OFF_XB);
  __bf16* WqkvT = (__bf16*)(ws + OFF_WQKVT);
  __bf16* WoT   = (__bf16*)(ws + OFF_WOT);
  __bf16* QKVb  = (__bf16*)(ws + OFF_QKV);
  __bf16* AOb   = (__bf16*)(ws + OFF_AO);
  __bf16* VTb   = (__bf16*)(ws + OFF_VT);

  // 1. prep: weights transpose-convert + x convert, one launch
  prep_all<<<dim3(224, 64), 256, 0, stream>>>(x, wq, wk, wv, wo, Xb, WqkvT, WoT);
  // 2. QKV projection: 8-phase 256x192, 16x16 = 256 blocks (full fill), 2-tile unroll
  gemm8p_qkv<<<dim3(16, 16), 512, 0, stream>>>(Xb, WqkvT, QKVb, 4096, 3072, 2048);
  // 3. transpose V into VT (V is not RoPE'd)
  vt_kernel<<<dim3(32, 4, 16), 256, 0, stream>>>(QKVb, VTb);
  // 4. RoPE K only (Q-rope fused into attention)
  ropek_kernel<<<4096 * 4 * 16 / 256, 256, 0, stream>>>(QKVb, cosb, sinb);
  // 5. attention: R15 structure (Q-tile 64, balanced pairs, single barrier, defer-max)
  attn_kernel<<<dim3(8, 16, 4), 256, 0, stream>>>(QKVb, VTb, cosb, sinb, AOb);
  // 6. output projection: 2-phase 256x128, 16x16 = 256 blocks, 2-tile unroll
  gemm2p<<<dim3(16, 16), 512, 0, stream>>>(AOb, WoT, out, 4096, 2048, 2048);
}

// Round 18
// 163.487 us; speedup vs baseline: 1.0508x; 1.0083x over previous
//
#include <hip/hip_runtime.h>

typedef __attribute__((ext_vector_type(8))) __bf16 bf16x8;
typedef __attribute__((ext_vector_type(4))) __bf16 bf16x4;
typedef __attribute__((ext_vector_type(4))) float f32x4;

#define DEV static __device__ __forceinline__

DEV void gload_lds16(const void* g, void* l) {
  __builtin_amdgcn_global_load_lds((const __attribute__((address_space(1))) void*)g,
                                   (__attribute__((address_space(3))) void*)l, 16, 0, 0);
}

DEV void lgkm0_sb() {
  asm volatile("s_waitcnt lgkmcnt(0)" ::: "memory");
  __builtin_amdgcn_sched_barrier(0);
}

// ------------- prep: transpose-convert all weights + convert x, ONE launch -------------
__global__ void prep_all(const float* __restrict__ x, const float* __restrict__ wq,
                         const float* __restrict__ wk, const float* __restrict__ wv,
                         const float* __restrict__ wo, __bf16* __restrict__ Xb,
                         __bf16* __restrict__ WqkvT, __bf16* __restrict__ WoT) {
  int bx = blockIdx.x;
  if (bx >= 160) {
    size_t vb = (size_t)(bx - 160) * 64 + blockIdx.y;
    size_t i = (vb * 256 + threadIdx.x) * 8;
    float4 a = *(const float4*)(x + i);
    float4 b = *(const float4*)(x + i + 4);
    bf16x8 o;
    o[0] = (__bf16)a.x; o[1] = (__bf16)a.y; o[2] = (__bf16)a.z; o[3] = (__bf16)a.w;
    o[4] = (__bf16)b.x; o[5] = (__bf16)b.y; o[6] = (__bf16)b.z; o[7] = (__bf16)b.w;
    *(bf16x8*)(Xb + i) = o;
    return;
  }
  __shared__ float tile[32][33];
  const float* src;
  __bf16* dst;
  int N, n0, drow;
  if (bx < 64)      { src = wq; dst = WqkvT; N = 2048; n0 = bx * 32;        drow = n0; }
  else if (bx < 80) { src = wk; dst = WqkvT; N = 512;  n0 = (bx - 64) * 32; drow = 2048 + n0; }
  else if (bx < 96) { src = wv; dst = WqkvT; N = 512;  n0 = (bx - 80) * 32; drow = 2560 + n0; }
  else              { src = wo; dst = WoT;   N = 2048; n0 = (bx - 96) * 32; drow = n0; }
  int k0 = blockIdx.y * 32;
  int tx = threadIdx.x & 31, ty = threadIdx.x >> 5;
  #pragma unroll
  for (int i = 0; i < 32; i += 8)
    tile[ty + i][tx] = src[(size_t)(k0 + ty + i) * N + n0 + tx];
  __syncthreads();
  #pragma unroll
  for (int i = 0; i < 32; i += 8)
    dst[(size_t)(drow + ty + i) * 2048 + k0 + tx] = (__bf16)tile[tx][ty + i];
}

// ------------- post-QKV: V transpose + K RoPE, ONE launch (disjoint data, concurrent) -------------
// bx [0,2048):  vt — VT[(b*4+kvh)*128 + d][s] = V[b*1024+s][kvh*128+d]
// bx [2048,3072): ropek — RoPE in place on K columns of QKV
__global__ void postqkv_kernel(const __bf16* __restrict__ QKVc, __bf16* __restrict__ QKV,
                               __bf16* __restrict__ VT, const float* __restrict__ cosb,
                               const float* __restrict__ sinb) {
  int bx = blockIdx.x;
  if (bx < 2048) {
    __shared__ __bf16 t[32][33];
    int sx = bx & 31;
    int dx = (bx >> 5) & 3;
    int bk = bx >> 7;
    int b = bk >> 2, kvh = bk & 3;
    int tx = threadIdx.x & 31, ty = threadIdx.x >> 5;
    #pragma unroll
    for (int i = 0; i < 32; i += 8)
      t[ty + i][tx] = QKVc[(size_t)(b * 1024 + sx * 32 + ty + i) * 3072 + 2560 + kvh * 128 + dx * 32 + tx];
    __syncthreads();
    #pragma unroll
    for (int i = 0; i < 32; i += 8)
      VT[((size_t)bk * 128 + dx * 32 + ty + i) * 1024 + sx * 32 + tx] = t[tx][ty + i];
    return;
  }
  int gid = (bx - 2048) * 256 + threadIdx.x;  // total 4096*4*16
  int p = gid & 15;
  int ht = gid >> 4;
  int hc = ht & 3;
  int tok = ht >> 2;
  int s = tok & 1023;
  __bf16* base = QKV + (size_t)tok * 3072 + 2048 + hc * 128;
  int d0 = p * 4;
  const float* cr = cosb + s * 128;
  const float* sr = sinb + s * 128;
  float x0[4], x1[4];
  #pragma unroll
  for (int j = 0; j < 4; ++j) {
    x0[j] = (float)base[d0 + j];
    x1[j] = (float)base[d0 + 64 + j];
  }
  #pragma unroll
  for (int j = 0; j < 4; ++j) {
    float n0 = x0[j] * cr[d0 + j] - x1[j] * sr[d0 + j];
    float n1 = x1[j] * cr[d0 + 64 + j] + x0[j] * sr[d0 + 64 + j];
    base[d0 + j] = (__bf16)n0;
    base[d0 + 64 + j] = (__bf16)n1;
  }
}

// ================= 8-phase GEMM 256x192 (QKV) — R14-proven (2-tile unroll, static bufs) =================
__global__ __launch_bounds__(512, 2) void gemm8p_qkv(const __bf16* __restrict__ A,
                                                     const __bf16* __restrict__ Bt,
                                                     __bf16* __restrict__ C,
                                                     int M, int N, int K) {
  constexpr int ABYTES = 256 * 64 * 2;   // 32 KB
  constexpr int BBYTES = 192 * 64 * 2;   // 24 KB
  __shared__ alignas(1024) char smem[2 * (ABYTES + BBYTES)];  // 112 KB

  const int tid = threadIdx.x;
  const int l = tid & 63, w = tid >> 6;
  const int wr = w >> 2, wc = w & 3;
  const int g = l >> 4, ln = l & 15;

  const int nbx = gridDim.x;  // 16
  const int nwg = nbx * gridDim.y;
  int lin = blockIdx.y * nbx + blockIdx.x;
  lin = (lin & 7) * (nwg >> 3) + (lin >> 3);  // bijective: 256 % 8 == 0
  const int brow = (lin / nbx) * 256, bcol = (lin % nbx) * 192;

  const __bf16* Ag = A + (size_t)brow * K;
  const __bf16* Bg = Bt + (size_t)bcol * K;
  const int NT = K / 64;  // 32

  f32x4 acc[8][3] = {};

  auto chunk = [&](const __bf16* gb, char* lb, int ktc, int sub) {
    int r16 = l >> 2;
    int colb = ((l & 3) * 16) ^ (((l >> 5) & 1) << 5);
    int row = (sub >> 1) * 16 + r16;
    gload_lds16(gb + (size_t)row * K + ktc * 64 + (sub & 1) * 32 + (colb >> 1),
                lb + sub * 1024 + l * 16);
  };
  auto stA0 = [&](int ktc, char* ab) {
    #pragma unroll
    for (int i = 0; i < 2; ++i) { int idx = i * 8 + w; chunk(Ag, ab, ktc, (idx >> 3) * 16 + (idx & 7)); }
  };
  auto stA1 = [&](int ktc, char* ab) {
    #pragma unroll
    for (int i = 0; i < 2; ++i) { int idx = i * 8 + w; chunk(Ag, ab, ktc, 8 + (idx >> 3) * 16 + (idx & 7)); }
  };
  auto stBg0 = [&](int ktc, char* bb) {
    #pragma unroll
    for (int i = 0; i < 2; ++i) {
      int t = i * 8 + w;
      int sub = ((t >> 2) * 3 + ((t >> 1) & 1)) * 2 + (t & 1);
      chunk(Bg, bb, ktc, sub);
    }
  };
  auto stBg1 = [&](int ktc, char* bb) {
    int sub = ((w >> 1) * 3 + 2) * 2 + (w & 1);
    chunk(Bg, bb, ktc, sub);
  };

  auto ldA = [&](const char* ab, int m, int kk) -> bf16x8 {
    int sub = (wr * 8 + m) * 2 + kk;
    return *(const bf16x8*)(ab + sub * 1024 + ln * 64 + ((g * 16) ^ (((ln >> 3) & 1) << 5)));
  };
  auto ldB = [&](const char* bb, int nf, int kk) -> bf16x8 {
    int sub = (wc * 3 + nf) * 2 + kk;
    return *(const bf16x8*)(bb + sub * 1024 + ln * 64 + ((g * 16) ^ (((ln >> 3) & 1) << 5)));
  };

  auto bar = [&]() {
    __builtin_amdgcn_sched_barrier(0);
    __builtin_amdgcn_s_barrier();
    __builtin_amdgcn_sched_barrier(0);
  };

  char* const A0 = smem;
  char* const A1 = smem + ABYTES;
  char* const B0 = smem + 2 * ABYTES;
  char* const B1 = smem + 2 * ABYTES + BBYTES;

  stA0(0, A0); stBg0(0, B0); stBg1(0, B0); stA1(0, A0);
  stA0(1, A1); stBg0(1, B1); stBg1(1, B1); stA1(1, A1);
  asm volatile("s_waitcnt vmcnt(10)" ::: "memory");
  __builtin_amdgcn_sched_barrier(0);
  bar();

  bf16x8 af[4][2], bfv[3][2];

#define QKV_TILE(KT, AB, BB)                                                                      \
  do {                                                                                            \
    const int ktc = ((KT) + 2) & 31;                                                              \
    _Pragma("unroll")                                                                             \
    for (int m = 0; m < 4; ++m) { af[m][0] = ldA(AB, m, 0); af[m][1] = ldA(AB, m, 1); }           \
    _Pragma("unroll")                                                                             \
    for (int nf = 0; nf < 2; ++nf) { bfv[nf][0] = ldB(BB, nf, 0); bfv[nf][1] = ldB(BB, nf, 1); }  \
    bar();                                                                                        \
    lgkm0_sb();                                                                                   \
    __builtin_amdgcn_s_setprio(1);                                                                \
    _Pragma("unroll")                                                                             \
    for (int m = 0; m < 4; ++m)                                                                   \
      _Pragma("unroll")                                                                           \
      for (int nf = 0; nf < 2; ++nf)                                                              \
        _Pragma("unroll")                                                                         \
        for (int kk = 0; kk < 2; ++kk)                                                            \
          acc[m][nf] = __builtin_amdgcn_mfma_f32_16x16x32_bf16(af[m][kk], bfv[nf][kk],            \
                                                               acc[m][nf], 0, 0, 0);              \
    __builtin_amdgcn_s_setprio(0);                                                                \
    asm volatile("s_waitcnt vmcnt(9)" ::: "memory");                                              \
    __builtin_amdgcn_sched_barrier(0);                                                            \
    bar();                                                                                        \
    bfv[2][0] = ldB(BB, 2, 0); bfv[2][1] = ldB(BB, 2, 1);                                         \
    stA0(ktc, AB); stBg0(ktc, BB);                                                                \
    bar();                                                                                        \
    lgkm0_sb();                                                                                   \
    __builtin_amdgcn_s_setprio(1);                                                                \
    _Pragma("unroll")                                                                             \
    for (int m = 0; m < 4; ++m)                                                                   \
      _Pragma("unroll")                                                                           \
      for (int kk = 0; kk < 2; ++kk)                                                              \
        acc[m][2] = __builtin_amdgcn_mfma_f32_16x16x32_bf16(af[m][kk], bfv[2][kk],                \
                                                            acc[m][2], 0, 0, 0);                  \
    __builtin_amdgcn_s_setprio(0);                                                                \
    asm volatile("s_waitcnt vmcnt(11)" ::: "memory");                                             \
    __builtin_amdgcn_sched_barrier(0);                                                            \
    bar();                                                                                        \
    _Pragma("unroll")                                                                             \
    for (int m = 0; m < 4; ++m) { af[m][0] = ldA(AB, 4 + m, 0); af[m][1] = ldA(AB, 4 + m, 1); }   \
    stBg1(ktc, BB);                                                                               \
    bar();                                                                                        \
    lgkm0_sb();                                                                                   \
    __builtin_amdgcn_s_setprio(1);                                                                \
    _Pragma("unroll")                                                                             \
    for (int m = 0; m < 4; ++m)                                                                   \
      _Pragma("unroll")                                                                           \
      for (int nf = 0; nf < 2; ++nf)                                                              \
        _Pragma("unroll")                                                                         \
        for (int kk = 0; kk < 2; ++kk)                                                            \
          acc[4 + m][nf] = __builtin_amdgcn_mfma_f32_16x16x32_bf16(af[m][kk], bfv[nf][kk],        \
                                                                   acc[4 + m][nf], 0, 0, 0);      \
    __builtin_amdgcn_s_setprio(0);                                                                \
    bar();                                                                                        \
    stA1(ktc, AB);                                                                                \
    bar();                                                                                        \
    lgkm0_sb();                                                                                   \
    __builtin_amdgcn_s_setprio(1);                                                                \
    _Pragma("unroll")                                                                             \
    for (int m = 0; m < 4; ++m)                                                                   \
      _Pragma("unroll")                                                                           \
      for (int kk = 0; kk < 2; ++kk)                                                              \
        acc[4 + m][2] = __builtin_amdgcn_mfma_f32_16x16x32_bf16(af[m][kk], bfv[2][kk],            \
                                                                acc[4 + m][2], 0, 0, 0);          \
    __builtin_amdgcn_s_setprio(0);                                                                \
    asm volatile("s_waitcnt vmcnt(10)" ::: "memory");                                             \
    __builtin_amdgcn_sched_barrier(0);                                                            \
    bar();                                                                                        \
  } while (0)

  for (int ktp = 0; ktp < NT; ktp += 2) {
    QKV_TILE(ktp, A0, B0);
    QKV_TILE(ktp + 1, A1, B1);
  }
#undef QKV_TILE

  #pragma unroll
  for (int mi = 0; mi < 8; ++mi)
    #pragma unroll
    for (int nf = 0; nf < 3; ++nf)
      #pragma unroll
      for (int j = 0; j < 4; ++j) {
        size_t r = brow + wr * 128 + mi * 16 + g * 4 + j;
        size_t c = bcol + wc * 48 + nf * 16 + ln;
        C[r * N + c] = (__bf16)acc[mi][nf][j];
      }
}

// ================= 2-phase GEMM 256x128 (out-proj) — R14-proven =================
__global__ __launch_bounds__(512, 2) void gemm2p(const __bf16* __restrict__ A,
                                                 const __bf16* __restrict__ Bt,
                                                 float* __restrict__ C,
                                                 int M, int N, int K) {
  constexpr int ABYTES = 256 * 64 * 2;   // 32 KB
  constexpr int BBYTES = 128 * 64 * 2;   // 16 KB
  __shared__ alignas(1024) char smem[2 * (ABYTES + BBYTES)];  // 96 KB

  const int tid = threadIdx.x;
  const int l = tid & 63, w = tid >> 6;
  const int wr = w >> 1, wc = w & 1;
  const int g = l >> 4, ln = l & 15;

  const int nbx = gridDim.x;  // 16
  const int nwg = nbx * gridDim.y;
  int lin = blockIdx.y * nbx + blockIdx.x;
  lin = (lin & 7) * (nwg >> 3) + (lin >> 3);
  const int brow = (lin / nbx) * 256, bcol = (lin % nbx) * 128;

  const __bf16* Ag = A + (size_t)brow * K;
  const __bf16* Bg = Bt + (size_t)bcol * K;
  const int NT = K / 64;

  f32x4 acc[4][4] = {};

  auto chunk = [&](const __bf16* gb, char* lb, int ktc, int sub) {
    int r16 = l >> 2;
    int colb = ((l & 3) * 16) ^ (((l >> 5) & 1) << 5);
    int row = (sub >> 1) * 16 + r16;
    gload_lds16(gb + (size_t)row * K + ktc * 64 + (sub & 1) * 32 + (colb >> 1),
                lb + sub * 1024 + l * 16);
  };
  auto stAp0 = [&](int ktc, char* ab) {
    #pragma unroll
    for (int i = 0; i < 2; ++i) { int t = i * 8 + w; chunk(Ag, ab, ktc, (t >> 2) * 8 + (t & 3)); }
  };
  auto stAp1 = [&](int ktc, char* ab) {
    #pragma unroll
    for (int i = 0; i < 2; ++i) { int t = i * 8 + w; chunk(Ag, ab, ktc, (t >> 2) * 8 + 4 + (t & 3)); }
  };
  auto stB = [&](int ktc, char* bb) {
    #pragma unroll
    for (int i = 0; i < 2; ++i) { int t = i * 8 + w; chunk(Bg, bb, ktc, t); }
  };

  auto ldA = [&](const char* ab, int mi, int kk) -> bf16x8 {
    int sub = (wr * 4 + mi) * 2 + kk;
    return *(const bf16x8*)(ab + sub * 1024 + ln * 64 + ((g * 16) ^ (((ln >> 3) & 1) << 5)));
  };
  auto ldB = [&](const char* bb, int nf, int kk) -> bf16x8 {
    int sub = (wc * 4 + nf) * 2 + kk;
    return *(const bf16x8*)(bb + sub * 1024 + ln * 64 + ((g * 16) ^ (((ln >> 3) & 1) << 5)));
  };

  auto vm6 = [&]() {
    asm volatile("s_waitcnt vmcnt(6)" ::: "memory");
    __builtin_amdgcn_sched_barrier(0);
  };
  auto bar = [&]() {
    __builtin_amdgcn_sched_barrier(0);
    __builtin_amdgcn_s_barrier();
    __builtin_amdgcn_sched_barrier(0);
  };

  char* const A0 = smem;
  char* const A1 = smem + ABYTES;
  char* const B0 = smem + 2 * ABYTES;
  char* const B1 = smem + 2 * ABYTES + BBYTES;

  stAp0(0, A0); stB(0, B0);
  stAp1(0, A0);
  stAp0(1, A1); stB(1, B1);
  vm6();
  bar();

  bf16x8 af[2][2], bfv[4][2];

#define OP_TILE(KT, AB, BB, ABo)                                                                  \
  do {                                                                                            \
    const int ktc1 = ((KT) + 1) & 31;                                                             \
    const int ktc2 = ((KT) + 2) & 31;                                                             \
    _Pragma("unroll")                                                                             \
    for (int mi = 0; mi < 2; ++mi) { af[mi][0] = ldA(AB, mi, 0); af[mi][1] = ldA(AB, mi, 1); }    \
    _Pragma("unroll")                                                                             \
    for (int nf = 0; nf < 4; ++nf) { bfv[nf][0] = ldB(BB, nf, 0); bfv[nf][1] = ldB(BB, nf, 1); }  \
    stAp1(ktc1, ABo);                                                                             \
    bar();                                                                                        \
    lgkm0_sb();                                                                                   \
    __builtin_amdgcn_s_setprio(1);                                                                \
    _Pragma("unroll")                                                                             \
    for (int mi = 0; mi < 2; ++mi)                                                                \
      _Pragma("unroll")                                                                           \
      for (int nf = 0; nf < 4; ++nf)                                                              \
        _Pragma("unroll")                                                                         \
        for (int kk = 0; kk < 2; ++kk)                                                            \
          acc[mi][nf] = __builtin_amdgcn_mfma_f32_16x16x32_bf16(af[mi][kk], bfv[nf][kk],          \
                                                                acc[mi][nf], 0, 0, 0);            \
    __builtin_amdgcn_s_setprio(0);                                                                \
    vm6();                                                                                        \
    bar();                                                                                        \
    _Pragma("unroll")                                                                             \
    for (int mi = 0; mi < 2; ++mi) { af[mi][0] = ldA(AB, 2 + mi, 0); af[mi][1] = ldA(AB, 2 + mi, 1); } \
    stAp0(ktc2, AB); stB(ktc2, BB);                                                               \
    bar();                                                                                        \
    lgkm0_sb();                                                                                   \
    __builtin_amdgcn_s_setprio(1);                                                                \
    _Pragma("unroll")                                                                             \
    for (int mi = 0; mi < 2; ++mi)                                                                \
      _Pragma("unroll")                                                                           \
      for (int nf = 0; nf < 4; ++nf)                                                              \
        _Pragma("unroll")                                                                         \
        for (int kk = 0; kk < 2; ++kk)                                                            \
          acc[2 + mi][nf] = __builtin_amdgcn_mfma_f32_16x16x32_bf16(af[mi][kk], bfv[nf][kk],      \
                                                                    acc[2 + mi][nf], 0, 0, 0);    \
    __builtin_amdgcn_s_setprio(0);                                                                \
    vm6();                                                                                        \
    bar();                                                                                        \
  } while (0)

  for (int ktp = 0; ktp < NT; ktp += 2) {
    OP_TILE(ktp, A0, B0, A1);
    OP_TILE(ktp + 1, A1, B1, A0);
  }
#undef OP_TILE

  #pragma unroll
  for (int mi = 0; mi < 4; ++mi)
    #pragma unroll
    for (int nf = 0; nf < 4; ++nf)
      #pragma unroll
      for (int j = 0; j < 4; ++j) {
        size_t r = brow + wr * 64 + mi * 16 + g * 4 + j;
        size_t c = bcol + wc * 64 + nf * 16 + ln;
        C[r * N + c] = acc[mi][nf][j];
      }
}

// ---------------- Flash attention (R15-proven): Q-tile 64, 4 waves, 2 blocks/CU ----------------
__global__ __launch_bounds__(256, 2) void attn_kernel(const __bf16* __restrict__ QKV,
                                                      const __bf16* __restrict__ VT,
                                                      const float* __restrict__ cosb,
                                                      const float* __restrict__ sinb,
                                                      __bf16* __restrict__ AO) {
  __shared__ __bf16 Kl[2][64 * 128];
  __shared__ __bf16 Vt[2][128 * 64];
  __shared__ __bf16 Pl[4][16 * 72];

  const int tid = threadIdx.x, l = tid & 63, w = tid >> 6;
  const int h = blockIdx.y, b = blockIdx.z;
  const int kvh = h >> 2;
  const int g = l >> 4, ln = l & 15;
  const __bf16* VTg = VT + (size_t)(b * 4 + kvh) * 128 * 1024;
  const float scsc = 0.08838834764831845f;  // 1/sqrt(128)

  auto stageK = [&](int buf, int kt) {
    const __bf16* Kg = QKV + (size_t)(b * 1024 + kt * 64) * 3072 + 2048 + kvh * 128;
    #pragma unroll
    for (int i = 0; i < 4; ++i) {
      int r = i * 16 + (tid >> 4);
      int c = tid & 15;
      int csw = c ^ (r & 7);
      gload_lds16(Kg + (size_t)r * 3072 + csw * 8, (char*)&Kl[buf][0] + i * 4096 + tid * 16);
    }
  };
  auto stageV = [&](int buf, int kt) {
    #pragma unroll
    for (int i = 0; i < 4; ++i) {
      int ci = i * 256 + tid;
      int row = ci >> 3;
      int c = ci & 7;
      int csw = c ^ (row & 7);
      gload_lds16(VTg + (size_t)row * 1024 + kt * 64 + csw * 8, (char*)&Vt[buf][0] + (size_t)ci * 16);
    }
  };

  #pragma unroll 1
  for (int pass = 0; pass < 2; ++pass) {
    const int qt = pass ? 15 - (int)blockIdx.x : (int)blockIdx.x;
    const size_t tokQ = (size_t)b * 1024 + qt * 64;
    const int srow = qt * 64 + w * 16 + ln;

    bf16x8 qf[4];
    {
      const __bf16* qp = QKV + (tokQ + w * 16 + ln) * 3072 + h * 128;
      bf16x8 qraw[4];
      #pragma unroll
      for (int ks = 0; ks < 4; ++ks) qraw[ks] = *(const bf16x8*)(qp + ks * 32 + g * 8);
      const float* cr = cosb + (size_t)srow * 128;
      const float* sr = sinb + (size_t)srow * 128;
      #pragma unroll
      for (int ks2 = 0; ks2 < 2; ++ks2)
        #pragma unroll
        for (int j = 0; j < 8; ++j) {
          int d = ks2 * 32 + g * 8 + j;
          float lo = (float)qraw[ks2][j], hi = (float)qraw[ks2 + 2][j];
          float c0 = cr[d], s0 = sr[d];
          qf[ks2][j]     = (__bf16)(lo * c0 - hi * s0);
          qf[ks2 + 2][j] = (__bf16)(hi * c0 + lo * s0);
        }
    }

    float mrow = -1e30f, lrow = 0.f;
    f32x4 acco[8] = {};

    __syncthreads();
    stageK(0, 0); stageV(0, 0);
    int cur = 0;

    for (int kt = 0; kt <= qt; ++kt) {
      __syncthreads();

      if (kt < qt) { stageK(cur ^ 1, kt + 1); stageV(cur ^ 1, kt + 1); }

      f32x4 accs[4] = {};
      __builtin_amdgcn_s_setprio(1);
      #pragma unroll
      for (int cb = 0; cb < 4; ++cb) {
        int row = cb * 16 + ln;
        #pragma unroll
        for (int ks = 0; ks < 4; ++ks) {
          bf16x8 kb = *(const bf16x8*)((const char*)&Kl[cur][0] + row * 256 +
                                       (((ks * 4 + g) ^ (row & 7)) * 16));
          accs[cb] = __builtin_amdgcn_mfma_f32_16x16x32_bf16(kb, qf[ks], accs[cb], 0, 0, 0);
        }
      }
      __builtin_amdgcn_s_setprio(0);

      const bool diag = (kt == qt);
      #pragma unroll
      for (int cb = 0; cb < 4; ++cb)
        #pragma unroll
        for (int j = 0; j < 4; ++j) {
          float s = accs[cb][j] * scsc;
          if (diag && (cb * 16 + g * 4 + j > w * 16 + ln)) s = -1e30f;
          accs[cb][j] = s;
        }

      float mt = accs[0][0];
      #pragma unroll
      for (int cb = 0; cb < 4; ++cb)
        #pragma unroll
        for (int j = 0; j < 4; ++j) mt = fmaxf(mt, accs[cb][j]);
      mt = fmaxf(mt, __shfl_xor(mt, 16, 64));
      mt = fmaxf(mt, __shfl_xor(mt, 32, 64));
      if (!__all(mt <= mrow + 8.0f)) {
        float mnew = fmaxf(mrow, mt);
        float corr = __expf(mrow - mnew);
        mrow = mnew;
        lrow *= corr;
        #pragma unroll
        for (int n = 0; n < 8; ++n)
          #pragma unroll
          for (int j = 0; j < 4; ++j) acco[n][j] *= corr;
      }
      float rs = 0.f;
      #pragma unroll
      for (int cb = 0; cb < 4; ++cb)
        #pragma unroll
        for (int j = 0; j < 4; ++j) {
          float p = __expf(accs[cb][j] - mrow);
          accs[cb][j] = p;
          rs += p;
        }
      rs += __shfl_xor(rs, 16, 64);
      rs += __shfl_xor(rs, 32, 64);
      lrow += rs;

      #pragma unroll
      for (int cb = 0; cb < 4; ++cb) {
        bf16x4 pw;
        #pragma unroll
        for (int j = 0; j < 4; ++j) pw[j] = (__bf16)accs[cb][j];
        *(bf16x4*)(&Pl[w][ln * 72 + cb * 16 + g * 4]) = pw;
      }
      lgkm0_sb();

      __builtin_amdgcn_s_setprio(1);
      #pragma unroll
      for (int sc = 0; sc < 2; ++sc) {
        bf16x8 pa = *(const bf16x8*)(&Pl[w][ln * 72 + sc * 32 + g * 8]);
        #pragma unroll
        for (int n = 0; n < 8; ++n) {
          int row = n * 16 + ln;
          bf16x8 vb = *(const bf16x8*)((const char*)&Vt[cur][0] + row * 128 +
                                       (((sc * 4 + g) ^ (row & 7)) * 16));
          acco[n] = __builtin_amdgcn_mfma_f32_16x16x32_bf16(vb, pa, acco[n], 0, 0, 0);
        }
      }
      __builtin_amdgcn_s_setprio(0);
      cur ^= 1;
    }

    float rl = 1.f / lrow;
    size_t r = tokQ + w * 16 + ln;
    #pragma unroll
    for (int n = 0; n < 8; ++n) {
      bf16x4 ov;
      #pragma unroll
      for (int j = 0; j < 4; ++j) ov[j] = (__bf16)(acco[n][j] * rl);
      *(bf16x4*)(&AO[r * 2048 + h * 128 + n * 16 + g * 4]) = ov;
    }
  }
}

// ---------------- launch ----------------
extern "C" void kernel_launch(void* const* d_in, const int* in_sizes, int n_in,
                              void* d_out, int out_size, void* d_ws, size_t ws_size,
                              hipStream_t stream) {
  const float* x    = (const float*)d_in[0];
  const float* cosb = (const float*)d_in[1];
  const float* sinb = (const float*)d_in[2];
  const float* wq   = (const float*)d_in[3];
  const float* wk   = (const float*)d_in[4];
  const float* wv   = (const float*)d_in[5];
  const float* wo   = (const float*)d_in[6];
  float* out = (float*)d_out;

  char* ws = (char*)d_ws;
  const size_t OFF_XB    = 0;                       // 4096*2048 bf16 = 16 MiB (dead after gemm#1)
  const size_t OFF_WQKVT = OFF_XB + 16777216;       // 3072*2048 bf16 = 12 MiB
  const size_t OFF_WOT   = OFF_WQKVT + 12582912;    // 2048*2048 bf16 = 8 MiB
  const size_t OFF_QKV   = OFF_WOT + 8388608;       // 4096*3072 bf16 = 24 MiB
  const size_t OFF_AO    = OFF_QKV + 25165824;      // 4096*2048 bf16 = 16 MiB
  const size_t OFF_VT    = OFF_XB;                  // 16*128*1024 bf16 = 4 MiB, aliases Xb

  __bf16* Xb    = (__bf16*)(ws + OFF_XB);
  __bf16* WqkvT = (__bf16*)(ws + OFF_WQKVT);
  __bf16* WoT   = (__bf16*)(ws + OFF_WOT);
  __bf16* QKVb  = (__bf16*)(ws + OFF_QKV);
  __bf16* AOb   = (__bf16*)(ws + OFF_AO);
  __bf16* VTb   = (__bf16*)(ws + OFF_VT);

  // 1. prep: weights transpose-convert + x convert, one launch
  prep_all<<<dim3(224, 64), 256, 0, stream>>>(x, wq, wk, wv, wo, Xb, WqkvT, WoT);
  // 2. QKV projection: 8-phase 256x192, 16x16 = 256 blocks (full fill), 2-tile unroll
  gemm8p_qkv<<<dim3(16, 16), 512, 0, stream>>>(Xb, WqkvT, QKVb, 4096, 3072, 2048);
  // 3. post-QKV: V transpose + K RoPE (disjoint, concurrent, one launch)
  postqkv_kernel<<<dim3(3072), 256, 0, stream>>>(QKVb, QKVb, VTb, cosb, sinb);
  // 4. attention: R15 structure (Q-tile 64, balanced pairs, single barrier, defer-max)
  attn_kernel<<<dim3(8, 16, 4), 256, 0, stream>>>(QKVb, VTb, cosb, sinb, AOb);
  // 5. output projection: 2-phase 256x128, 16x16 = 256 blocks, 2-tile unroll
  gemm2p<<<dim3(16, 16), 512, 0, stream>>>(AOb, WoT, out, 4096, 2048, 2048);
}